// Round 4
// baseline (2171.913 us; speedup 1.0000x reference)
//
#include <hip/hip_runtime.h>

// Elman ReLU RNN, round 4: single-wave recurrence, barrier-free inner loop.
//
// r1/r3 post-mortem: step time (~2140 cyc) is invariant to LDS traffic and FMA
// count -> the binder is the per-step s_barrier + fully-exposed latency at
// 1 wave/SIMD, not any pipe. Fix: remove the per-step barrier.
//
// 256 blocks (1 batch/CU) x 192 threads (3 waves):
//   wave 0 (h): owns the entire recurrence. Lane ln holds W_hh rows ln and
//     ln+64 in 232 VGPRs (legal: 1 wave/SIMD -> 512-VGPR budget, no spill
//     through ~450 per m08). Per step: 29 broadcast ds_read_b128 of h[t-1]
//     + 232 FMA + 2 ds_write_b32. Same-wave LDS RAW ordering via lgkmcnt --
//     NO barrier per step.
//   wave 1 (xp): produces xp windows one super-step (16 steps) ahead into a
//     double-buffered LDS window; x streamed from global with distance-2
//     register prefetch (covers ~900cyc HBM latency).
//   wave 2 (fc): consumes h windows one super-step behind, stores out.
// One lgkm-only s_barrier per 16 steps (130 total vs 2048 before).
//
// All weights pinned via empty asm ("+v") after load: blocks the r2 failure
// mode where the allocator re-materialized loop-invariant weights from global
// every step (FETCH doubled).
// f32 throughout: the recurrence amplifies per-step noise ~1e3x; bf16 anywhere
// in the loop blows the 2.6e-2 threshold.

namespace {
constexpr int kB = 256;
constexpr int kT = 2048;
constexpr int kI = 50;
constexpr int kH = 116;
constexpr int kO = 50;
constexpr int kR = 16;        // steps per super-step (barrier period)
constexpr int kS = kT / kR;   // 128 super-steps
}

struct Smem {
  alignas(16) float h[2][kR][128];    // [window][slot][j]: h[t] at [(t/kR)&1][t%kR]
  alignas(8) float2 xp2[2][kR][64];   // per lane: (xp[t][ln], xp[t][ln+64])
};

__device__ __forceinline__ void sync_lds() {
  // lgkm-only drain: global x loads / out stores stay in flight.
  __asm__ __volatile__("s_waitcnt lgkmcnt(0)\n\ts_barrier" ::: "memory");
}
__device__ __forceinline__ void pin4(float4& v) {
  __asm__ __volatile__("" : "+v"(v.x), "+v"(v.y), "+v"(v.z), "+v"(v.w));
}
__device__ __forceinline__ void pinf(float& v) {
  __asm__ __volatile__("" : "+v"(v));
}

// ---------------- wave 0: recurrence ----------------
__device__ void run_h(Smem& sm, const float* __restrict__ W_hh, int ln) {
  const bool hasB = (64 + ln) < kH;
  const int rB = hasB ? (64 + ln) : 0;
  float4 wa[29], wb[29];
  {
    const float4* wra = (const float4*)(W_hh + ln * kH);   // 464B rows, 16B aligned
    const float4* wrb = (const float4*)(W_hh + rB * kH);
#pragma unroll
    for (int i = 0; i < 29; ++i) { wa[i] = wra[i]; pin4(wa[i]); }
#pragma unroll
    for (int i = 0; i < 29; ++i) { wb[i] = wrb[i]; pin4(wb[i]); }
  }
  // h[-1] = 0 lives where (s=0, i=0) reads: window 1, slot kR-1.
  sm.h[1][kR - 1][ln] = 0.f;
  sm.h[1][kR - 1][64 + ln] = 0.f;
  sync_lds();  // barrier #0

#pragma unroll 1
  for (int s = 0; s < kS; ++s) {
    const int cw = s & 1;
#pragma unroll 1
    for (int i = 0; i < kR; ++i) {
      const float4* h4 =
          (const float4*)((i == 0) ? sm.h[cw ^ 1][kR - 1] : sm.h[cw][i - 1]);
      float a0 = 0.f, a1 = 0.f, a2 = 0.f, a3 = 0.f;
      float b0 = 0.f, b1 = 0.f, b2 = 0.f, b3 = 0.f;
#pragma unroll
      for (int k = 0; k < 29; ++k) {
        const float4 v = h4[k];
        a0 = fmaf(wa[k].x, v.x, a0);
        a1 = fmaf(wa[k].y, v.y, a1);
        a2 = fmaf(wa[k].z, v.z, a2);
        a3 = fmaf(wa[k].w, v.w, a3);
        b0 = fmaf(wb[k].x, v.x, b0);
        b1 = fmaf(wb[k].y, v.y, b1);
        b2 = fmaf(wb[k].z, v.z, b2);
        b3 = fmaf(wb[k].w, v.w, b3);
      }
      const float2 xv = sm.xp2[cw][i][ln];
      float ha = ((a0 + a1) + (a2 + a3)) + xv.x;
      float hb = ((b0 + b1) + (b2 + b3)) + xv.y;
      ha = ha > 0.f ? ha : 0.f;
      hb = hb > 0.f ? hb : 0.f;
      sm.h[cw][i][ln] = ha;            // rows 0..63
      if (hasB) sm.h[cw][i][64 + ln] = hb;  // rows 64..115
    }
    sync_lds();  // seal window cw for fc; release xp window cw^1
  }
}

// ---------------- wave 1: xp producer ----------------
__device__ __forceinline__ void x_load(float2 (&X)[25], const float* xrow) {
  const float2* p = (const float2*)xrow;  // 200B rows, 8B aligned
#pragma unroll
  for (int i = 0; i < 25; ++i) X[i] = p[i];
}

__device__ __forceinline__ void xp_store(Smem& sm, int w, int i,
                                         const float2 (&X)[25],
                                         const float (&wi0)[kI],
                                         const float (&wi1)[kI], float bias0,
                                         float bias1, int ln) {
  float s00 = 0.f, s01 = 0.f, s02 = 0.f, s03 = 0.f;
  float s10 = 0.f, s11 = 0.f, s12 = 0.f, s13 = 0.f;
#pragma unroll
  for (int q = 0; q < 12; ++q) {
    const float2 p = X[2 * q];
    const float2 r = X[2 * q + 1];
    s00 = fmaf(wi0[4 * q + 0], p.x, s00);
    s01 = fmaf(wi0[4 * q + 1], p.y, s01);
    s02 = fmaf(wi0[4 * q + 2], r.x, s02);
    s03 = fmaf(wi0[4 * q + 3], r.y, s03);
    s10 = fmaf(wi1[4 * q + 0], p.x, s10);
    s11 = fmaf(wi1[4 * q + 1], p.y, s11);
    s12 = fmaf(wi1[4 * q + 2], r.x, s12);
    s13 = fmaf(wi1[4 * q + 3], r.y, s13);
  }
  const float2 pt = X[24];
  s00 = fmaf(wi0[48], pt.x, s00);
  s01 = fmaf(wi0[49], pt.y, s01);
  s10 = fmaf(wi1[48], pt.x, s10);
  s11 = fmaf(wi1[49], pt.y, s11);
  sm.xp2[w][i][ln] = make_float2(bias0 + ((s00 + s01) + (s02 + s03)),
                                 bias1 + ((s10 + s11) + (s12 + s13)));
}

__device__ void run_xp(Smem& sm, const float* __restrict__ xb,
                       const float* __restrict__ W_ih,
                       const float* __restrict__ b_ih,
                       const float* __restrict__ b_hh, int ln) {
  float wi0[kI], wi1[kI];
  float bias0, bias1 = 0.f;
  {
    const float2* wr = (const float2*)(W_ih + ln * kI);
#pragma unroll
    for (int i = 0; i < 25; ++i) { wi0[2 * i] = wr[i].x; wi0[2 * i + 1] = wr[i].y; }
#pragma unroll
    for (int i = 0; i < kI; ++i) pinf(wi0[i]);
    bias0 = b_ih[ln] + b_hh[ln];
  }
  if (ln < kH - 64) {
    const float2* wr = (const float2*)(W_ih + (ln + 64) * kI);
#pragma unroll
    for (int i = 0; i < 25; ++i) { wi1[2 * i] = wr[i].x; wi1[2 * i + 1] = wr[i].y; }
    bias1 = b_ih[ln + 64] + b_hh[ln + 64];
  } else {
#pragma unroll
    for (int i = 0; i < kI; ++i) wi1[i] = 0.f;
  }
#pragma unroll
  for (int i = 0; i < kI; ++i) pinf(wi1[i]);

  float2 A[25], B[25];
  x_load(A, xb + 0 * kI);
  x_load(B, xb + 1 * kI);
  // Fill window 0 (t = 0..kR-1); epilogue prefetches x[kR], x[kR+1].
#pragma unroll 1
  for (int i = 0; i < kR; i += 2) {
    xp_store(sm, 0, i, A, wi0, wi1, bias0, bias1, ln);
    x_load(A, xb + (size_t)(i + 2) * kI);
    xp_store(sm, 0, i + 1, B, wi0, wi1, bias0, bias1, ln);
    x_load(B, xb + (size_t)(i + 3) * kI);
  }
  sync_lds();  // barrier #0

#pragma unroll 1
  for (int s = 0; s < kS; ++s) {
    if (s < kS - 1) {
      const int w = (s + 1) & 1;
      const int tb = (s + 1) * kR;
#pragma unroll 1
      for (int i = 0; i < kR; i += 2) {
        xp_store(sm, w, i, A, wi0, wi1, bias0, bias1, ln);
        int tf = tb + i + 2;
        tf = tf < kT ? tf : kT - 1;
        x_load(A, xb + (size_t)tf * kI);
        xp_store(sm, w, i + 1, B, wi0, wi1, bias0, bias1, ln);
        tf = tb + i + 3;
        tf = tf < kT ? tf : kT - 1;
        x_load(B, xb + (size_t)tf * kI);
      }
    }
    sync_lds();
  }
}

// ---------------- wave 2: fc consumer ----------------
__device__ __forceinline__ void fc_window(Smem& sm, int s, const float4 (&wf)[29],
                                          float bfc, float* __restrict__ ob,
                                          int ln, bool act) {
  const int w = s & 1;
#pragma unroll 1
  for (int i = 0; i < kR; ++i) {
    const float4* h4 = (const float4*)sm.h[w][i];
    float c0 = bfc, c1 = 0.f, c2 = 0.f, c3 = 0.f;
#pragma unroll
    for (int k = 0; k < 29; ++k) {
      const float4 v = h4[k];
      c0 = fmaf(wf[k].x, v.x, c0);
      c1 = fmaf(wf[k].y, v.y, c1);
      c2 = fmaf(wf[k].z, v.z, c2);
      c3 = fmaf(wf[k].w, v.w, c3);
    }
    if (act) ob[(size_t)(s * kR + i) * kO + ln] = (c0 + c1) + (c2 + c3);
  }
}

__device__ void run_fc(Smem& sm, const float* __restrict__ W_fc,
                       const float* __restrict__ b_fc, float* __restrict__ ob,
                       int ln) {
  const bool act = ln < kO;
  const int r = act ? ln : 0;
  float4 wf[29];
  {
    const float4* wr = (const float4*)(W_fc + r * kH);
#pragma unroll
    for (int i = 0; i < 29; ++i) { wf[i] = wr[i]; pin4(wf[i]); }
  }
  const float bfc = act ? b_fc[r] : 0.f;
  sync_lds();  // barrier #0

#pragma unroll 1
  for (int s = 0; s < kS; ++s) {
    if (s > 0) fc_window(sm, s - 1, wf, bfc, ob, ln, act);
    sync_lds();
  }
  fc_window(sm, kS - 1, wf, bfc, ob, ln, act);  // after final barrier: sealed
}

__launch_bounds__(192, 1)
__global__ void rnn_fused(const float* __restrict__ x,
                          const float* __restrict__ W_ih,
                          const float* __restrict__ b_ih,
                          const float* __restrict__ W_hh,
                          const float* __restrict__ b_hh,
                          const float* __restrict__ W_fc,
                          const float* __restrict__ b_fc,
                          float* __restrict__ out) {
  __shared__ Smem sm;
  const int tid = threadIdx.x;
  const int wv = tid >> 6;
  const int ln = tid & 63;
  const int b = blockIdx.x;
  const float* xb = x + (size_t)b * (kT * kI);
  float* ob = out + (size_t)b * (kT * kO);

  if (wv == 0) {
    run_h(sm, W_hh, ln);
  } else if (wv == 1) {
    run_xp(sm, xb, W_ih, b_ih, b_hh, ln);
  } else {
    run_fc(sm, W_fc, b_fc, ob, ln);
  }
}

extern "C" void kernel_launch(void* const* d_in, const int* in_sizes, int n_in,
                              void* d_out, int out_size, void* d_ws, size_t ws_size,
                              hipStream_t stream) {
  (void)in_sizes; (void)n_in; (void)d_ws; (void)ws_size; (void)out_size;
  const float* x    = (const float*)d_in[0];
  const float* W_ih = (const float*)d_in[1];
  const float* b_ih = (const float*)d_in[2];
  const float* W_hh = (const float*)d_in[3];
  const float* b_hh = (const float*)d_in[4];
  const float* W_fc = (const float*)d_in[5];
  const float* b_fc = (const float*)d_in[6];
  float* out = (float*)d_out;
  rnn_fused<<<dim3(kB), dim3(192), 0, stream>>>(x, W_ih, b_ih, W_hh, b_hh,
                                                W_fc, b_fc, out);
}

// Round 5
// 1900.360 us; speedup vs baseline: 1.1429x; 1.1429x over previous
//
#include <hip/hip_runtime.h>

// Elman ReLU RNN, round 5: decoupled xp-precompute + straggler-free recurrence.
//
// r1-r4 model: per-step cost = issue + LDS RAW + barrier-coupled straggler
// stall. The xp wave (per-step global loads feeding the barrier) was the
// straggler. Fix: precompute xp = x·W_ih^T + b_ih + b_hh into d_ws with a
// separate parallel kernel; the recurrence kernel's h-waves read xp via a
// depth-4 per-lane register ring (1 global b32/step, no step-coupled latency).
//
// Kernel 2: 256 blocks (1 batch/CU) x 192 threads:
//   waves 0-1: h rows [0,58)/[58,116), one W_hh row (116 f32) per lane ->
//              ~148 VGPR, no spills (r2/r4 lesson: >230 demand = spill movs).
//   wave  2  : fc on h[t-1] from sealed LDS, fire-and-forget out stores.
// Per-step: 29 broadcast ds_read_b128 + 116 FMA per h-wave, one lgkm-only
// barrier. f32 throughout (recurrence amplifies per-step noise ~1e3-1e4x;
// bf16 anywhere in the chain blows the 2.6e-2 threshold).
//
// Fallback (ws too small, decided once host-side -> graph-stable): fc wave
// stages x rows into an LDS ring; h-waves compute their own xp row inline.

namespace {
constexpr int kT = 2048;
constexpr int kI = 50;
constexpr int kH = 116;
constexpr int kO = 50;
}

struct Smem {
  alignas(16) float h[2][128];   // h double buffer (parity t&1)
  alignas(16) float xr[4][52];   // fallback only: x ring (52 = 13 float4 pad)
};

__device__ __forceinline__ void sync_lds() {
  // Drains LDS only; global loads (xp ring) / stores (out) stay in flight.
  __asm__ __volatile__("s_waitcnt lgkmcnt(0)\n\ts_barrier" ::: "memory");
}

// ============ Kernel 1: xp[b][t][j] = W_ih[j]·x[b][t] + b_ih[j] + b_hh[j] ====
__launch_bounds__(256, 1)
__global__ void xp_kernel(const float* __restrict__ x,
                          const float* __restrict__ W_ih,
                          const float* __restrict__ b_ih,
                          const float* __restrict__ b_hh,
                          float* __restrict__ xp) {
  const int tid = threadIdx.x, wv = tid >> 6, ln = tid & 63;
  const int b = blockIdx.x >> 1;
  const int t0 = (blockIdx.x & 1) * (kT / 2);
  const int r1 = 64 + ln;
  const bool has1 = r1 < kH;
  float wi0[kI], wi1[kI], bias0, bias1 = 0.f;
  {
    const float2* w = (const float2*)(W_ih + ln * kI);  // 200B rows, 8B aligned
#pragma unroll
    for (int i = 0; i < 25; ++i) { wi0[2 * i] = w[i].x; wi0[2 * i + 1] = w[i].y; }
    bias0 = b_ih[ln] + b_hh[ln];
  }
  if (has1) {
    const float2* w = (const float2*)(W_ih + r1 * kI);
#pragma unroll
    for (int i = 0; i < 25; ++i) { wi1[2 * i] = w[i].x; wi1[2 * i + 1] = w[i].y; }
    bias1 = b_ih[r1] + b_hh[r1];
  } else {
#pragma unroll
    for (int i = 0; i < kI; ++i) wi1[i] = 0.f;
  }
  for (int t = t0 + wv; t < t0 + kT / 2; t += 4) {
    const float2* xr = (const float2*)(x + ((size_t)b * kT + t) * kI);
    float s00 = 0.f, s01 = 0.f, s10 = 0.f, s11 = 0.f;
#pragma unroll
    for (int i = 0; i < 25; ++i) {
      const float2 v = xr[i];
      s00 = fmaf(wi0[2 * i], v.x, s00);
      s01 = fmaf(wi0[2 * i + 1], v.y, s01);
      s10 = fmaf(wi1[2 * i], v.x, s10);
      s11 = fmaf(wi1[2 * i + 1], v.y, s11);
    }
    float* xo = xp + ((size_t)b * kT + t) * kH;
    xo[ln] = bias0 + s00 + s01;
    if (has1) xo[r1] = bias1 + s10 + s11;
  }
}

// ============ Kernel 2: recurrence + fused fc ===============================
template <int C, bool PRE>
__device__ __forceinline__ void h_step(Smem& sm, int t0, const float4 (&wh)[29],
                                       const float (&wi)[kI], float bias,
                                       const float* __restrict__ xpg, float& xq,
                                       bool act, int row) {
  const float4* hp = (const float4*)sm.h[(C + 1) & 1];  // h[t-1]
  float a0, a1 = 0.f, a2 = 0.f, a3 = 0.f;
  if constexpr (PRE) {
    a0 = xq;  // bias already baked in by xp_kernel
  } else {
    a0 = bias;
    const float4* x4 = (const float4*)sm.xr[C & 3];
#pragma unroll
    for (int i = 0; i < 12; ++i) {
      const float4 v = x4[i];
      a0 = fmaf(wi[4 * i + 0], v.x, a0);
      a1 = fmaf(wi[4 * i + 1], v.y, a1);
      a2 = fmaf(wi[4 * i + 2], v.z, a2);
      a3 = fmaf(wi[4 * i + 3], v.w, a3);
    }
    const float2 vt = ((const float2*)sm.xr[C & 3])[24];
    a0 = fmaf(wi[48], vt.x, a0);
    a1 = fmaf(wi[49], vt.y, a1);
  }
#pragma unroll
  for (int i = 0; i < 29; ++i) {
    const float4 v = hp[i];
    a0 = fmaf(wh[i].x, v.x, a0);
    a1 = fmaf(wh[i].y, v.y, a1);
    a2 = fmaf(wh[i].z, v.z, a2);
    a3 = fmaf(wh[i].w, v.w, a3);
  }
  float hn = (a0 + a1) + (a2 + a3);
  hn = hn > 0.f ? hn : 0.f;
  if (act) sm.h[C & 1][row] = hn;
  if constexpr (PRE) {
    int tf = t0 + C + 4;
    tf = tf < kT ? tf : kT - 1;
    xq = xpg[(size_t)tf * kH];  // ring refill, consumed 4 steps later
  }
  sync_lds();
}

template <int C, bool PRE>
__device__ __forceinline__ void fc_step(Smem& sm, int t0, const float4 (&wf)[29],
                                        float bfc, float* __restrict__ ob,
                                        const float* __restrict__ xbrow,
                                        float& xs, int ln) {
  const int t = t0 + C;
  if (t > 0) {
    const float4* hp = (const float4*)sm.h[(C + 1) & 1];  // h[t-1]
    float c0 = bfc, c1 = 0.f, c2 = 0.f, c3 = 0.f;
#pragma unroll
    for (int i = 0; i < 29; ++i) {
      const float4 v = hp[i];
      c0 = fmaf(wf[i].x, v.x, c0);
      c1 = fmaf(wf[i].y, v.y, c1);
      c2 = fmaf(wf[i].z, v.z, c2);
      c3 = fmaf(wf[i].w, v.w, c3);
    }
    if (ln < kO) ob[(size_t)(t - 1) * kO + ln] = (c0 + c1) + (c2 + c3);
  }
  if constexpr (!PRE) {
    if (ln < kI) {
      sm.xr[(C + 2) & 3][ln] = xs;  // stage x[t+2]
      int tf = t + 4;
      tf = tf < kT ? tf : kT - 1;
      xs = xbrow[(size_t)tf * kI + ln];
    }
  }
  sync_lds();
}

template <bool PRE>
__launch_bounds__(192, 1)
__global__ void rnn_kernel(const float* __restrict__ x,
                           const float* __restrict__ xp,
                           const float* __restrict__ W_ih,
                           const float* __restrict__ b_ih,
                           const float* __restrict__ W_hh,
                           const float* __restrict__ b_hh,
                           const float* __restrict__ W_fc,
                           const float* __restrict__ b_fc,
                           float* __restrict__ out) {
  __shared__ Smem sm;
  const int tid = threadIdx.x, wv = tid >> 6, ln = tid & 63;
  const int b = blockIdx.x;
  float* ob = out + (size_t)b * (kT * kO);

  if (wv < 2) {
    // ---- h-waves: rows [0,58) / [58,116) ----
    const bool act = ln < 58;
    const int row = wv * 58 + (act ? ln : 57);
    float4 wh[29];
    {
      const float4* wr = (const float4*)(W_hh + row * kH);  // 464B rows, 16B ok
#pragma unroll
      for (int i = 0; i < 29; ++i) wh[i] = wr[i];
    }
    float wi[kI];
    float bias = 0.f;
    const float* xpg = nullptr;
    float xq0 = 0.f, xq1 = 0.f, xq2 = 0.f, xq3 = 0.f;
    if constexpr (PRE) {
      xpg = xp + (size_t)b * kT * kH + row;
      xq0 = xpg[0 * (size_t)kH];
      xq1 = xpg[1 * (size_t)kH];
      xq2 = xpg[2 * (size_t)kH];
      xq3 = xpg[3 * (size_t)kH];
    } else {
      const float2* w = (const float2*)(W_ih + row * kI);
#pragma unroll
      for (int i = 0; i < 25; ++i) { wi[2 * i] = w[i].x; wi[2 * i + 1] = w[i].y; }
      bias = b_ih[row] + b_hh[row];
    }
    if (tid < 128) { sm.h[0][tid] = 0.f; sm.h[1][tid] = 0.f; }
    sync_lds();  // barrier #0
#pragma unroll 1
    for (int t0 = 0; t0 < kT; t0 += 4) {
      h_step<0, PRE>(sm, t0, wh, wi, bias, xpg, xq0, act, row);
      h_step<1, PRE>(sm, t0, wh, wi, bias, xpg, xq1, act, row);
      h_step<2, PRE>(sm, t0, wh, wi, bias, xpg, xq2, act, row);
      h_step<3, PRE>(sm, t0, wh, wi, bias, xpg, xq3, act, row);
    }
  } else {
    // ---- fc wave ----
    const int fr = (ln < kO) ? ln : kO - 1;
    float4 wf[29];
    {
      const float4* wr = (const float4*)(W_fc + fr * kH);
#pragma unroll
      for (int i = 0; i < 29; ++i) wf[i] = wr[i];
    }
    const float bfc = b_fc[fr];
    const float* xbrow = x + (size_t)b * kT * kI;
    float xA = 0.f, xB = 0.f;
    if constexpr (!PRE) {
      if (ln < kI) {
        sm.xr[0][ln] = xbrow[0 * kI + ln];
        sm.xr[1][ln] = xbrow[1 * kI + ln];
        xA = xbrow[2 * kI + ln];
        xB = xbrow[3 * kI + ln];
      }
    }
    sync_lds();  // barrier #0
#pragma unroll 1
    for (int t0 = 0; t0 < kT; t0 += 4) {
      fc_step<0, PRE>(sm, t0, wf, bfc, ob, xbrow, xA, ln);
      fc_step<1, PRE>(sm, t0, wf, bfc, ob, xbrow, xB, ln);
      fc_step<2, PRE>(sm, t0, wf, bfc, ob, xbrow, xA, ln);
      fc_step<3, PRE>(sm, t0, wf, bfc, ob, xbrow, xB, ln);
    }
    // out[kT-1] from h[kT-1] (parity 1), sealed by the loop's final barrier.
    {
      const float4* hp = (const float4*)sm.h[(kT - 1) & 1];
      float c0 = bfc, c1 = 0.f, c2 = 0.f, c3 = 0.f;
#pragma unroll
      for (int i = 0; i < 29; ++i) {
        const float4 v = hp[i];
        c0 = fmaf(wf[i].x, v.x, c0);
        c1 = fmaf(wf[i].y, v.y, c1);
        c2 = fmaf(wf[i].z, v.z, c2);
        c3 = fmaf(wf[i].w, v.w, c3);
      }
      if (ln < kO) ob[(size_t)(kT - 1) * kO + ln] = (c0 + c1) + (c2 + c3);
    }
  }
}

extern "C" void kernel_launch(void* const* d_in, const int* in_sizes, int n_in,
                              void* d_out, int out_size, void* d_ws, size_t ws_size,
                              hipStream_t stream) {
  (void)in_sizes; (void)n_in; (void)out_size;
  const float* x    = (const float*)d_in[0];
  const float* W_ih = (const float*)d_in[1];
  const float* b_ih = (const float*)d_in[2];
  const float* W_hh = (const float*)d_in[3];
  const float* b_hh = (const float*)d_in[4];
  const float* W_fc = (const float*)d_in[5];
  const float* b_fc = (const float*)d_in[6];
  float* out = (float*)d_out;
  const int B = 256;
  const size_t xp_bytes = (size_t)B * kT * kH * sizeof(float);  // 243 MB
  if (ws_size >= xp_bytes) {  // ws_size constant across calls -> graph-stable
    float* xp = (float*)d_ws;
    xp_kernel<<<dim3(2 * B), dim3(256), 0, stream>>>(x, W_ih, b_ih, b_hh, xp);
    rnn_kernel<true><<<dim3(B), dim3(192), 0, stream>>>(
        x, xp, W_ih, b_ih, W_hh, b_hh, W_fc, b_fc, out);
  } else {
    rnn_kernel<false><<<dim3(B), dim3(192), 0, stream>>>(
        x, nullptr, W_ih, b_ih, W_hh, b_hh, W_fc, b_fc, out);
  }
}